// Round 2
// baseline (213.578 us; speedup 1.0000x reference)
//
#include <hip/hip_runtime.h>
#include <hip/hip_bf16.h>
#include <hip/hip_cooperative_groups.h>

namespace cg = cooperative_groups;

#define N_NODES 4096
#define C_CH    8
#define IN_DIM  256
#define D_DIM   64
#define CD      512
#define OUT_DIM 128
#define ITERS   4
#define STRIDE  128     // max degree slack (mean 41, sd 6.4; 128 is >13 sigma)

typedef __hip_bfloat16 bf16;
typedef short short8 __attribute__((ext_vector_type(8)));
typedef float floatx4 __attribute__((ext_vector_type(4)));

__device__ __forceinline__ float bf2f(bf16 x) { return __bfloat162float(x); }

__device__ __forceinline__ unsigned f2b_rne(float x) {
    unsigned u = __float_as_uint(x);
    return (u + 0x7FFFu + ((u >> 16) & 1u)) >> 16;
}
__device__ __forceinline__ unsigned pack2bf(float a, float b) {
    return f2b_rne(a) | (f2b_rne(b) << 16);
}
__device__ __forceinline__ void unpack2(unsigned v, float& a, float& b) {
    a = __uint_as_float(v << 16);
    b = __uint_as_float(v & 0xFFFF0000u);
}
__device__ __forceinline__ short8 as_s8(uint4 u) {
    union { uint4 a; short8 b; } x; x.a = u; return x.b;
}

// VALU-pipe butterfly step: x + dpp_move(x). No DS unit involvement.
// CTRL: 0xB1 = quad_perm(1,0,3,2) -> xor1 ; 0x4E = quad_perm(2,3,0,1) -> xor2
//       0x141 = row_half_mirror -> quad swap within 8 ; 0x128 = row_ror:8
template<int CTRL>
__device__ __forceinline__ float dpp_add(float x) {
    int yi = __builtin_amdgcn_update_dpp(0, __float_as_int(x), CTRL, 0xF, 0xF, true);
    return x + __int_as_float(yi);
}

// Per-wave dtype detect from first 64 dwords of features.
__device__ __forceinline__ bool wave_detect(const unsigned* __restrict__ feat_u) {
    int lane = threadIdx.x & 63;
    unsigned u = feat_u[lane];
    int e = (u >> 7) & 0xFF;
    int vote = (e >= 0x68 && e <= 0x86) ? 1 : 0;
    #pragma unroll
    for (int off = 32; off; off >>= 1) vote += __shfl_xor(vote, off);
    return vote >= 32;
}

// ---------------------------------------------------------------------------
// Stage A: blocks [0,8) -> Wt[col][k] bf16 (LDS-tiled transpose of W);
//          blocks [8,72) -> Wo_t[n][k] bf16.
// ---------------------------------------------------------------------------
__global__ __launch_bounds__(256) void stage_a(
        const void* __restrict__ feat, const void* __restrict__ W,
        const void* __restrict__ Wo,
        unsigned short* __restrict__ Wt, unsigned short* __restrict__ Wo_t) {
    bool isbf = wave_detect((const unsigned*)feat);
    int bx = blockIdx.x, t = threadIdx.x;
    if (bx < 8) {
        __shared__ __align__(16) unsigned short lt[IN_DIM * D_DIM];   // 32 KB [k][d]
        int c = bx;
        if (isbf) {
            const uint4* p = (const uint4*)((const unsigned short*)W + (size_t)c * IN_DIM * D_DIM);
            #pragma unroll
            for (int i = 0; i < 8; i++) {
                int idx = t + i * 256;
                *(uint4*)&lt[idx * 8] = p[idx];
            }
        } else {
            const float4* p = (const float4*)((const float*)W + (size_t)c * IN_DIM * D_DIM);
            #pragma unroll
            for (int i = 0; i < 16; i++) {
                int idx = t + i * 256;
                float4 f = p[idx];
                uint2 v = make_uint2(pack2bf(f.x, f.y), pack2bf(f.z, f.w));
                *(uint2*)&lt[idx * 4] = v;
            }
        }
        __syncthreads();
        uint4* wt4 = (uint4*)Wt;
        #pragma unroll
        for (int i = 0; i < 8; i++) {
            int j = t + i * 256;
            int d = j >> 5, seg = j & 31;
            int k0 = seg * 8;
            unsigned short v[8];
            #pragma unroll
            for (int k = 0; k < 8; k++) v[k] = lt[(k0 + k) * D_DIM + d];
            uint4 o;
            o.x = v[0] | ((unsigned)v[1] << 16);
            o.y = v[2] | ((unsigned)v[3] << 16);
            o.z = v[4] | ((unsigned)v[5] << 16);
            o.w = v[6] | ((unsigned)v[7] << 16);
            wt4[(c * 64 + d) * 32 + seg] = o;
        }
    } else {
        int base = (bx - 8) * 1024 + t * 4;
        #pragma unroll
        for (int q = 0; q < 4; q++) {
            int idx = base + q;
            int k = idx >> 7, n = idx & 127;
            unsigned short v;
            if (isbf) v = ((const unsigned short*)Wo)[idx];
            else      v = (unsigned short)f2b_rne(((const float*)Wo)[idx]);
            Wo_t[n * CD + k] = v;
        }
    }
}

// ---------------------------------------------------------------------------
// Stage B: blocks [0,256) -> MFMA projection (16 rows x 512 cols per block,
// wave w covers cols w*128.. = channels 2w,2w+1); blocks [256,1280) -> build.
// C/D layout: col=lane&15, row=quad*4+reg (HW-verified).
// ---------------------------------------------------------------------------
__global__ __launch_bounds__(256) void stage_b(
        const void* __restrict__ feat, const void* __restrict__ adj,
        const void* __restrict__ b, const unsigned short* __restrict__ Wt,
        unsigned* __restrict__ zbf, int* __restrict__ deg,
        int* __restrict__ col_buf) {
    bool isbf = wave_detect((const unsigned*)feat);
    int bx = blockIdx.x, t = threadIdx.x;
    int w = t >> 6, lane = t & 63;
    __shared__ __align__(16) unsigned short zt[16 * CD];   // 16 KB

    if (bx < 256) {
        int r0 = bx * 16;
        int n0 = w * 128;
        int m = lane & 15, quad = lane >> 4;
        int row = r0 + m;
        floatx4 acc[8];
        #pragma unroll
        for (int j = 0; j < 8; j++) acc[j] = (floatx4){0.f, 0.f, 0.f, 0.f};
        const uint4* wt4 = (const uint4*)Wt;

        if (isbf) {
            const uint4* a4 = (const uint4*)feat + (size_t)row * 32 + quad;
            #pragma unroll
            for (int k0 = 0; k0 < 8; k0++) {
                short8 a = as_s8(a4[k0 * 4]);
                #pragma unroll
                for (int j = 0; j < 8; j++) {
                    int col = n0 + j * 16 + m;
                    short8 bb = as_s8(wt4[col * 32 + k0 * 4 + quad]);
                    acc[j] = __builtin_amdgcn_mfma_f32_16x16x32_bf16(a, bb, acc[j], 0, 0, 0);
                }
            }
        } else {
            const float4* a4 = (const float4*)feat + (size_t)row * 64 + quad * 2;
            #pragma unroll
            for (int k0 = 0; k0 < 8; k0++) {
                float4 f0 = a4[k0 * 8], f1 = a4[k0 * 8 + 1];
                uint4 au;
                au.x = pack2bf(f0.x, f0.y); au.y = pack2bf(f0.z, f0.w);
                au.z = pack2bf(f1.x, f1.y); au.w = pack2bf(f1.z, f1.w);
                short8 a = as_s8(au);
                #pragma unroll
                for (int j = 0; j < 8; j++) {
                    int col = n0 + j * 16 + m;
                    short8 bb = as_s8(wt4[col * 32 + k0 * 4 + quad]);
                    acc[j] = __builtin_amdgcn_mfma_f32_16x16x32_bf16(a, bb, acc[j], 0, 0, 0);
                }
            }
        }

        float pre[8][4];
        #pragma unroll
        for (int j = 0; j < 8; j++) {
            int col = n0 + j * 16 + m;
            float bb = isbf ? bf2f(((const bf16*)b)[col]) : ((const float*)b)[col];
            #pragma unroll
            for (int r = 0; r < 4; r++) pre[j][r] = acc[j][r] + bb;
        }
        #pragma unroll
        for (int ch = 0; ch < 2; ch++) {
            float ss[4];
            #pragma unroll
            for (int r = 0; r < 4; r++) {
                float s = 0.f;
                #pragma unroll
                for (int jj = 0; jj < 4; jj++) {
                    float v = pre[ch * 4 + jj][r];
                    s = fmaf(v, v, s);
                }
                ss[r] = s;
            }
            #pragma unroll
            for (int off = 1; off < 16; off <<= 1) {
                #pragma unroll
                for (int r = 0; r < 4; r++) ss[r] += __shfl_xor(ss[r], off);
            }
            #pragma unroll
            for (int r = 0; r < 4; r++) {
                float sc = __builtin_amdgcn_rsqf(fmaxf(ss[r], 1e-12f));
                int lrow = quad * 4 + r;
                #pragma unroll
                for (int jj = 0; jj < 4; jj++) {
                    int j = ch * 4 + jj;
                    int col = n0 + j * 16 + m;
                    zt[lrow * CD + col] = (unsigned short)f2b_rne(pre[j][r] * sc);
                }
            }
        }
        __syncthreads();
        const uint4* zt4 = (const uint4*)zt;
        uint4* z4 = (uint4*)zbf;
        #pragma unroll
        for (int i = 0; i < 4; i++) {
            int j = t + i * 256;
            int lrow = j >> 6, seg = j & 63;
            z4[(size_t)(r0 + lrow) * 64 + seg] = zt4[j];
        }
    } else {
        // ----- build: one wave per adjacency row, shfl scan
        int i = (bx - 256) * 4 + w;
        int base_out = i * STRIDE;
        int running = 0;
        int nch = isbf ? 8 : 16;
        for (int ch = 0; ch < nch; ch++) {
            unsigned bits = 0;
            int j0, nelem;
            if (isbf) {
                const uint4* p = (const uint4*)((const unsigned short*)adj + (size_t)i * N_NODES);
                uint4 u = p[ch * 64 + lane];
                j0 = (ch * 64 + lane) * 8; nelem = 8;
                unsigned short h[8] = {
                    (unsigned short)(u.x & 0xFFFF), (unsigned short)(u.x >> 16),
                    (unsigned short)(u.y & 0xFFFF), (unsigned short)(u.y >> 16),
                    (unsigned short)(u.z & 0xFFFF), (unsigned short)(u.z >> 16),
                    (unsigned short)(u.w & 0xFFFF), (unsigned short)(u.w >> 16)};
                #pragma unroll
                for (int k = 0; k < 8; k++)
                    if ((h[k] & 0x8000) == 0 && h[k] != 0) bits |= (1u << k);
            } else {
                const float4* p = (const float4*)((const float*)adj + (size_t)i * N_NODES);
                float4 f = p[ch * 64 + lane];
                j0 = (ch * 64 + lane) * 4; nelem = 4;
                if (f.x > 0.f) bits |= 1u;
                if (f.y > 0.f) bits |= 2u;
                if (f.z > 0.f) bits |= 4u;
                if (f.w > 0.f) bits |= 8u;
            }
            int cnt = __popc(bits);
            int sc = cnt;
            #pragma unroll
            for (int off = 1; off < 64; off <<= 1) {
                int v = __shfl_up(sc, off);
                if (lane >= off) sc += v;
            }
            int tot = __shfl(sc, 63);
            int pos = base_out + running + (sc - cnt);
            for (int k = 0; k < nelem; k++) {
                if ((bits >> k) & 1u) {
                    if (pos < base_out + STRIDE) col_buf[pos] = j0 + k;
                    pos++;
                }
            }
            running += tot;
        }
        if (lane == 0) deg[i] = (running < STRIDE) ? running : STRIDE;
    }
}

// ---------------------------------------------------------------------------
// Routing, one WAVE per node. Per-edge dot reduce on VALU DPP (3 adds);
// softmax channel sum: row_ror:8 DPP + shfl_xor 16/32.
// Lane: g = lane>>3 (channel), s = lane&7 (dim octet).
// Two drivers:
//  - route_coop: ONE cooperative kernel, all 4 iterations, grid.sync between.
//    __launch_bounds__(256,4) forces VGPR<=128 -> 4 blocks/CU -> 1024 blocks
//    co-resident (cooperative-launch requirement).
//  - route_iter: single-iteration fallback (plain launch x4) if the
//    cooperative path is unavailable.
// ---------------------------------------------------------------------------
__device__ __forceinline__ void edge_step(const float zil2[8], float acc[8], uint4 u) {
    float vj[8];
    unpack2(u.x, vj[0], vj[1]);
    unpack2(u.y, vj[2], vj[3]);
    unpack2(u.z, vj[4], vj[5]);
    unpack2(u.w, vj[6], vj[7]);
    float p = 0.f;
    #pragma unroll
    for (int k = 0; k < 8; k++) p = fmaf(zil2[k], vj[k], p);
    // reduce over s (8 lanes) entirely on the VALU pipe
    p = dpp_add<0xB1>(p);      // xor1
    p = dpp_add<0x4E>(p);      // xor2
    p = dpp_add<0x141>(p);     // quad swap within 8
    float ex = __builtin_amdgcn_exp2f(p);   // exp(dot): zil2 pre-scaled by log2e
    // channel sum: stride 8 on DPP; strides 16/32 via DS shuffle
    float s = dpp_add<0x128>(ex);       // row_ror:8
    s += __shfl_xor(s, 16);
    s += __shfl_xor(s, 32);
    float wgt = ex * __builtin_amdgcn_rcpf(s);
    #pragma unroll
    for (int k = 0; k < 8; k++) acc[k] = fmaf(wgt, vj[k], acc[k]);
}

__device__ __forceinline__ void route_edges(const float zil2[8], float acc[8],
        const char* __restrict__ bin, const int* __restrict__ mycols, int dg,
        unsigned fragb) {
    int e = 0;
    for (; e + 3 < dg; e += 4) {
        int4 js = *(const int4*)&mycols[e];       // one ds_read_b128
        uint4 u0 = *(const uint4*)(bin + (((unsigned)js.x << 10) + fragb));
        uint4 u1 = *(const uint4*)(bin + (((unsigned)js.y << 10) + fragb));
        uint4 u2 = *(const uint4*)(bin + (((unsigned)js.z << 10) + fragb));
        uint4 u3 = *(const uint4*)(bin + (((unsigned)js.w << 10) + fragb));
        edge_step(zil2, acc, u0);
        edge_step(zil2, acc, u1);
        edge_step(zil2, acc, u2);
        edge_step(zil2, acc, u3);
    }
    for (; e < dg; e++) {
        uint4 u0 = *(const uint4*)(bin + (((unsigned)mycols[e] << 10) + fragb));
        edge_step(zil2, acc, u0);
    }
}

// l2-normalize acc over the 8 s-lanes of this channel group, write zi.
__device__ __forceinline__ void finish_norm(float acc[8], float zi[8]) {
    float ss = 0.f;
    #pragma unroll
    for (int k = 0; k < 8; k++) ss = fmaf(acc[k], acc[k], ss);
    ss = dpp_add<0xB1>(ss);
    ss = dpp_add<0x4E>(ss);
    ss = dpp_add<0x141>(ss);
    float sc = __builtin_amdgcn_rsqf(fmaxf(ss, 1e-12f));
    #pragma unroll
    for (int k = 0; k < 8; k++) zi[k] = acc[k] * sc;
}

__global__ __launch_bounds__(256, 4) void route_coop(
        unsigned* __restrict__ zbf_a, unsigned* __restrict__ zbf_b,
        const int* __restrict__ deg, const int* __restrict__ col_buf) {
    const float LOG2E = 1.4426950408889634f;
    int t = threadIdx.x;
    int w = t >> 6, lane = t & 63;
    int node = blockIdx.x * 4 + w;
    int g = lane >> 3, s = lane & 7;

    __shared__ __align__(16) int s_cols[4 * STRIDE];   // 2 KB, loaded ONCE
    {
        const int* src = col_buf + (size_t)blockIdx.x * (4 * STRIDE);
        s_cols[t]       = src[t]       & (N_NODES - 1);
        s_cols[t + 256] = src[t + 256] & (N_NODES - 1);
    }
    int dg = deg[node];
    __syncthreads();
    const int* mycols = s_cols + w * STRIDE;

    int frag = g * 32 + s * 4;              // dword index within 256-dword row
    unsigned fragb = (unsigned)frag << 2;   // byte offset within 1 KB row

    uint4 uown = *(const uint4*)(zbf_a + (size_t)node * 256 + frag);
    float zi[8];
    unpack2(uown.x, zi[0], zi[1]); unpack2(uown.y, zi[2], zi[3]);
    unpack2(uown.z, zi[4], zi[5]); unpack2(uown.w, zi[6], zi[7]);

    for (int it = 0; it < ITERS; it++) {
        const char* bin = (const char*)((it & 1) ? zbf_b : zbf_a);
        unsigned*   bot = (it & 1) ? zbf_a : zbf_b;

        float zil2[8], acc[8];
        #pragma unroll
        for (int k = 0; k < 8; k++) { zil2[k] = zi[k] * LOG2E; acc[k] = zi[k]; }

        route_edges(zil2, acc, bin, mycols, dg, fragb);
        finish_norm(acc, zi);

        uint4 ob;
        ob.x = pack2bf(zi[0], zi[1]); ob.y = pack2bf(zi[2], zi[3]);
        ob.z = pack2bf(zi[4], zi[5]); ob.w = pack2bf(zi[6], zi[7]);
        *(uint4*)(bot + (size_t)node * 256 + frag) = ob;

        if (it != ITERS - 1) {
            __threadfence();                 // device-scope: publish writes
            cg::this_grid().sync();          // iteration barrier
        }
    }
    // ITERS=4 even -> final state in zbf_a
}

__global__ __launch_bounds__(256) void route_iter(
        const unsigned* __restrict__ bin_u, unsigned* __restrict__ bot,
        const int* __restrict__ deg, const int* __restrict__ col_buf) {
    const float LOG2E = 1.4426950408889634f;
    int t = threadIdx.x;
    int w = t >> 6, lane = t & 63;
    int node = blockIdx.x * 4 + w;
    int g = lane >> 3, s = lane & 7;

    __shared__ __align__(16) int s_cols[4 * STRIDE];
    {
        const int* src = col_buf + (size_t)blockIdx.x * (4 * STRIDE);
        s_cols[t]       = src[t]       & (N_NODES - 1);
        s_cols[t + 256] = src[t + 256] & (N_NODES - 1);
    }
    int dg = deg[node];
    __syncthreads();
    const int* mycols = s_cols + w * STRIDE;

    int frag = g * 32 + s * 4;
    unsigned fragb = (unsigned)frag << 2;

    uint4 uown = *(const uint4*)(bin_u + (size_t)node * 256 + frag);
    float zi[8], zil2[8], acc[8];
    unpack2(uown.x, zi[0], zi[1]); unpack2(uown.y, zi[2], zi[3]);
    unpack2(uown.z, zi[4], zi[5]); unpack2(uown.w, zi[6], zi[7]);
    #pragma unroll
    for (int k = 0; k < 8; k++) { zil2[k] = zi[k] * LOG2E; acc[k] = zi[k]; }

    route_edges(zil2, acc, (const char*)bin_u, mycols, dg, fragb);
    finish_norm(acc, zi);

    uint4 ob;
    ob.x = pack2bf(zi[0], zi[1]); ob.y = pack2bf(zi[2], zi[3]);
    ob.z = pack2bf(zi[4], zi[5]); ob.w = pack2bf(zi[6], zi[7]);
    *(uint4*)(bot + (size_t)node * 256 + frag) = ob;
}

// ---------------------------------------------------------------------------
// Final GEMM via MFMA bf16: out[4096x128] = zbf[4096x512] @ Wo + bias.
// ---------------------------------------------------------------------------
__global__ __launch_bounds__(256) void out_gemm_mfma(
        const unsigned* __restrict__ zbf, const unsigned* __restrict__ wot_u,
        const void* __restrict__ bias, void* __restrict__ out,
        const void* __restrict__ feat) {
    bool isbf = wave_detect((const unsigned*)feat);
    int w = threadIdx.x >> 6, lane = threadIdx.x & 63;
    int r0 = blockIdx.x * 32 + (w & 1) * 16;
    int n0 = (w >> 1) * 64;
    int m = lane & 15, quad = lane >> 4;

    floatx4 acc0 = {0.f, 0.f, 0.f, 0.f}, acc1 = acc0, acc2 = acc0, acc3 = acc0;
    const unsigned* ap  = zbf   + (size_t)(r0 + m) * 256 + quad * 4;
    const unsigned* bp0 = wot_u + (size_t)(n0 + m) * 256 + quad * 4;
    const unsigned* bp1 = bp0 + 16 * 256;
    const unsigned* bp2 = bp0 + 32 * 256;
    const unsigned* bp3 = bp0 + 48 * 256;

    #pragma unroll
    for (int k0 = 0; k0 < 256; k0 += 16) {
        short8 a  = as_s8(*(const uint4*)(ap  + k0));
        short8 b0 = as_s8(*(const uint4*)(bp0 + k0));
        short8 b1 = as_s8(*(const uint4*)(bp1 + k0));
        short8 b2 = as_s8(*(const uint4*)(bp2 + k0));
        short8 b3 = as_s8(*(const uint4*)(bp3 + k0));
        acc0 = __builtin_amdgcn_mfma_f32_16x16x32_bf16(a, b0, acc0, 0, 0, 0);
        acc1 = __builtin_amdgcn_mfma_f32_16x16x32_bf16(a, b1, acc1, 0, 0, 0);
        acc2 = __builtin_amdgcn_mfma_f32_16x16x32_bf16(a, b2, acc2, 0, 0, 0);
        acc3 = __builtin_amdgcn_mfma_f32_16x16x32_bf16(a, b3, acc3, 0, 0, 0);
    }

    float accs[4][4] = {
        {acc0[0], acc0[1], acc0[2], acc0[3]},
        {acc1[0], acc1[1], acc1[2], acc1[3]},
        {acc2[0], acc2[1], acc2[2], acc2[3]},
        {acc3[0], acc3[1], acc3[2], acc3[3]}};
    #pragma unroll
    for (int c = 0; c < 4; c++) {
        int col = n0 + c * 16 + m;
        float bb = isbf ? bf2f(((const bf16*)bias)[col]) : ((const float*)bias)[col];
        #pragma unroll
        for (int r = 0; r < 4; r++) {
            int row = r0 + quad * 4 + r;
            float v = accs[c][r] + bb;
            size_t oi = (size_t)row * OUT_DIM + col;
            if (isbf) ((bf16*)out)[oi] = __float2bfloat16(v);
            else      ((float*)out)[oi] = v;
        }
    }
}

// ---------------------------------------------------------------------------
extern "C" void kernel_launch(void* const* d_in, const int* in_sizes, int n_in,
                              void* d_out, int out_size, void* d_ws, size_t ws_size,
                              hipStream_t stream) {
    const void* feat = d_in[0];
    const void* adj  = d_in[1];
    const void* W    = d_in[2];
    const void* b    = d_in[3];
    const void* Wo   = d_in[4];
    const void* bias = d_in[5];

    char* ws = (char*)d_ws;
    unsigned*       zbf_a   = (unsigned*)ws;                                // 4 MB
    unsigned*       zbf_b   = (unsigned*)(ws + (4u << 20));                 // 4 MB
    unsigned short* Wt      = (unsigned short*)(ws + (8u << 20));           // 256 KB
    unsigned short* Wo_t    = (unsigned short*)(ws + (8u << 20) + (256u << 10)); // 128 KB
    int*            deg     = (int*)(ws + (8u << 20) + (512u << 10));       // 16 KB
    int*            col_buf = (int*)(ws + (9u << 20));                      // 2 MB

    stage_a<<<72, 256, 0, stream>>>(feat, W, Wo, Wt, Wo_t);
    stage_b<<<1280, 256, 0, stream>>>(feat, adj, b, Wt, zbf_a, deg, col_buf);

    // Fused 4-iteration routing if the cooperative launch can fit all
    // 1024 blocks (needs 4 blocks/CU; __launch_bounds__(256,4) forces the
    // register budget). Otherwise: 4 plain launches of the same wave-per-node
    // kernel (correct under any occupancy).
    bool coop_done = false;
    {
        int nb = 0;
        hipError_t oe = hipOccupancyMaxActiveBlocksPerMultiprocessor(
                &nb, route_coop, 256, 0);
        if (oe == hipSuccess && nb >= 4) {
            void* args[4] = {(void*)&zbf_a, (void*)&zbf_b, (void*)&deg,
                             (void*)&col_buf};
            hipError_t le = hipLaunchCooperativeKernel(
                    reinterpret_cast<void*>(route_coop),
                    dim3(N_NODES / 4), dim3(256), args, 0, stream);
            coop_done = (le == hipSuccess);
        }
    }
    if (!coop_done) {
        unsigned* bin = zbf_a;
        unsigned* bot = zbf_b;
        for (int it = 0; it < ITERS; it++) {
            route_iter<<<N_NODES / 4, 256, 0, stream>>>(bin, bot, deg, col_buf);
            unsigned* tb = bin; bin = bot; bot = tb;
        }
    }

    // ITERS=4 even -> final state back in zbf_a
    out_gemm_mfma<<<N_NODES / 32, 256, 0, stream>>>(zbf_a, (const unsigned*)Wo_t,
                                                    bias, d_out, feat);
}

// Round 3
// 208.386 us; speedup vs baseline: 1.0249x; 1.0249x over previous
//
#include <hip/hip_runtime.h>
#include <hip/hip_bf16.h>

#define N_NODES 4096
#define C_CH    8
#define IN_DIM  256
#define D_DIM   64
#define CD      512
#define OUT_DIM 128
#define ITERS   4
#define STRIDE  128     // max degree slack (mean 41, sd 6.4; 128 is >13 sigma)

typedef __hip_bfloat16 bf16;
typedef short short8 __attribute__((ext_vector_type(8)));
typedef float floatx4 __attribute__((ext_vector_type(4)));

__device__ __forceinline__ float bf2f(bf16 x) { return __bfloat162float(x); }

__device__ __forceinline__ unsigned f2b_rne(float x) {
    unsigned u = __float_as_uint(x);
    return (u + 0x7FFFu + ((u >> 16) & 1u)) >> 16;
}
__device__ __forceinline__ unsigned pack2bf(float a, float b) {
    return f2b_rne(a) | (f2b_rne(b) << 16);
}
__device__ __forceinline__ void unpack2(unsigned v, float& a, float& b) {
    a = __uint_as_float(v << 16);
    b = __uint_as_float(v & 0xFFFF0000u);
}
__device__ __forceinline__ short8 as_s8(uint4 u) {
    union { uint4 a; short8 b; } x; x.a = u; return x.b;
}

// VALU-pipe butterfly step: x + dpp_move(x). No DS unit involvement.
// CTRL: 0xB1 = quad_perm(1,0,3,2) -> xor1 ; 0x4E = quad_perm(2,3,0,1) -> xor2
//       0x141 = row_half_mirror -> quad swap within 8 ; 0x128 = row_ror:8
template<int CTRL>
__device__ __forceinline__ float dpp_add(float x) {
    int yi = __builtin_amdgcn_update_dpp(0, __float_as_int(x), CTRL, 0xF, 0xF, true);
    return x + __int_as_float(yi);
}

// Per-wave dtype detect from first 64 dwords of features.
__device__ __forceinline__ bool wave_detect(const unsigned* __restrict__ feat_u) {
    int lane = threadIdx.x & 63;
    unsigned u = feat_u[lane];
    int e = (u >> 7) & 0xFF;
    int vote = (e >= 0x68 && e <= 0x86) ? 1 : 0;
    #pragma unroll
    for (int off = 32; off; off >>= 1) vote += __shfl_xor(vote, off);
    return vote >= 32;
}

// ---------------------------------------------------------------------------
// Stage A: blocks [0,8) -> Wt[col][k] bf16 (LDS-tiled transpose of W);
//          blocks [8,72) -> Wo_t[n][k] bf16.
// ---------------------------------------------------------------------------
__global__ __launch_bounds__(256) void stage_a(
        const void* __restrict__ feat, const void* __restrict__ W,
        const void* __restrict__ Wo,
        unsigned short* __restrict__ Wt, unsigned short* __restrict__ Wo_t) {
    bool isbf = wave_detect((const unsigned*)feat);
    int bx = blockIdx.x, t = threadIdx.x;
    if (bx < 8) {
        __shared__ __align__(16) unsigned short lt[IN_DIM * D_DIM];   // 32 KB [k][d]
        int c = bx;
        if (isbf) {
            const uint4* p = (const uint4*)((const unsigned short*)W + (size_t)c * IN_DIM * D_DIM);
            #pragma unroll
            for (int i = 0; i < 8; i++) {
                int idx = t + i * 256;
                *(uint4*)&lt[idx * 8] = p[idx];
            }
        } else {
            const float4* p = (const float4*)((const float*)W + (size_t)c * IN_DIM * D_DIM);
            #pragma unroll
            for (int i = 0; i < 16; i++) {
                int idx = t + i * 256;
                float4 f = p[idx];
                uint2 v = make_uint2(pack2bf(f.x, f.y), pack2bf(f.z, f.w));
                *(uint2*)&lt[idx * 4] = v;
            }
        }
        __syncthreads();
        uint4* wt4 = (uint4*)Wt;
        #pragma unroll
        for (int i = 0; i < 8; i++) {
            int j = t + i * 256;
            int d = j >> 5, seg = j & 31;
            int k0 = seg * 8;
            unsigned short v[8];
            #pragma unroll
            for (int k = 0; k < 8; k++) v[k] = lt[(k0 + k) * D_DIM + d];
            uint4 o;
            o.x = v[0] | ((unsigned)v[1] << 16);
            o.y = v[2] | ((unsigned)v[3] << 16);
            o.z = v[4] | ((unsigned)v[5] << 16);
            o.w = v[6] | ((unsigned)v[7] << 16);
            wt4[(c * 64 + d) * 32 + seg] = o;
        }
    } else {
        int base = (bx - 8) * 1024 + t * 4;
        #pragma unroll
        for (int q = 0; q < 4; q++) {
            int idx = base + q;
            int k = idx >> 7, n = idx & 127;
            unsigned short v;
            if (isbf) v = ((const unsigned short*)Wo)[idx];
            else      v = (unsigned short)f2b_rne(((const float*)Wo)[idx]);
            Wo_t[n * CD + k] = v;
        }
    }
}

// ---------------------------------------------------------------------------
// Stage B: blocks [0,256) -> MFMA projection (16 rows x 512 cols per block,
// wave w covers cols w*128.. = channels 2w,2w+1); blocks [256,1280) -> build.
// C/D layout: col=lane&15, row=quad*4+reg (HW-verified).
// ---------------------------------------------------------------------------
__global__ __launch_bounds__(256) void stage_b(
        const void* __restrict__ feat, const void* __restrict__ adj,
        const void* __restrict__ b, const unsigned short* __restrict__ Wt,
        unsigned* __restrict__ zbf, int* __restrict__ deg,
        int* __restrict__ col_buf) {
    bool isbf = wave_detect((const unsigned*)feat);
    int bx = blockIdx.x, t = threadIdx.x;
    int w = t >> 6, lane = t & 63;
    __shared__ __align__(16) unsigned short zt[16 * CD];   // 16 KB

    if (bx < 256) {
        int r0 = bx * 16;
        int n0 = w * 128;
        int m = lane & 15, quad = lane >> 4;
        int row = r0 + m;
        floatx4 acc[8];
        #pragma unroll
        for (int j = 0; j < 8; j++) acc[j] = (floatx4){0.f, 0.f, 0.f, 0.f};
        const uint4* wt4 = (const uint4*)Wt;

        if (isbf) {
            const uint4* a4 = (const uint4*)feat + (size_t)row * 32 + quad;
            #pragma unroll
            for (int k0 = 0; k0 < 8; k0++) {
                short8 a = as_s8(a4[k0 * 4]);
                #pragma unroll
                for (int j = 0; j < 8; j++) {
                    int col = n0 + j * 16 + m;
                    short8 bb = as_s8(wt4[col * 32 + k0 * 4 + quad]);
                    acc[j] = __builtin_amdgcn_mfma_f32_16x16x32_bf16(a, bb, acc[j], 0, 0, 0);
                }
            }
        } else {
            const float4* a4 = (const float4*)feat + (size_t)row * 64 + quad * 2;
            #pragma unroll
            for (int k0 = 0; k0 < 8; k0++) {
                float4 f0 = a4[k0 * 8], f1 = a4[k0 * 8 + 1];
                uint4 au;
                au.x = pack2bf(f0.x, f0.y); au.y = pack2bf(f0.z, f0.w);
                au.z = pack2bf(f1.x, f1.y); au.w = pack2bf(f1.z, f1.w);
                short8 a = as_s8(au);
                #pragma unroll
                for (int j = 0; j < 8; j++) {
                    int col = n0 + j * 16 + m;
                    short8 bb = as_s8(wt4[col * 32 + k0 * 4 + quad]);
                    acc[j] = __builtin_amdgcn_mfma_f32_16x16x32_bf16(a, bb, acc[j], 0, 0, 0);
                }
            }
        }

        float pre[8][4];
        #pragma unroll
        for (int j = 0; j < 8; j++) {
            int col = n0 + j * 16 + m;
            float bb = isbf ? bf2f(((const bf16*)b)[col]) : ((const float*)b)[col];
            #pragma unroll
            for (int r = 0; r < 4; r++) pre[j][r] = acc[j][r] + bb;
        }
        #pragma unroll
        for (int ch = 0; ch < 2; ch++) {
            float ss[4];
            #pragma unroll
            for (int r = 0; r < 4; r++) {
                float s = 0.f;
                #pragma unroll
                for (int jj = 0; jj < 4; jj++) {
                    float v = pre[ch * 4 + jj][r];
                    s = fmaf(v, v, s);
                }
                ss[r] = s;
            }
            #pragma unroll
            for (int off = 1; off < 16; off <<= 1) {
                #pragma unroll
                for (int r = 0; r < 4; r++) ss[r] += __shfl_xor(ss[r], off);
            }
            #pragma unroll
            for (int r = 0; r < 4; r++) {
                float sc = __builtin_amdgcn_rsqf(fmaxf(ss[r], 1e-12f));
                int lrow = quad * 4 + r;
                #pragma unroll
                for (int jj = 0; jj < 4; jj++) {
                    int j = ch * 4 + jj;
                    int col = n0 + j * 16 + m;
                    zt[lrow * CD + col] = (unsigned short)f2b_rne(pre[j][r] * sc);
                }
            }
        }
        __syncthreads();
        const uint4* zt4 = (const uint4*)zt;
        uint4* z4 = (uint4*)zbf;
        #pragma unroll
        for (int i = 0; i < 4; i++) {
            int j = t + i * 256;
            int lrow = j >> 6, seg = j & 63;
            z4[(size_t)(r0 + lrow) * 64 + seg] = zt4[j];
        }
    } else {
        // ----- build: one wave per adjacency row, shfl scan
        int i = (bx - 256) * 4 + w;
        int base_out = i * STRIDE;
        int running = 0;
        int nch = isbf ? 8 : 16;
        for (int ch = 0; ch < nch; ch++) {
            unsigned bits = 0;
            int j0, nelem;
            if (isbf) {
                const uint4* p = (const uint4*)((const unsigned short*)adj + (size_t)i * N_NODES);
                uint4 u = p[ch * 64 + lane];
                j0 = (ch * 64 + lane) * 8; nelem = 8;
                unsigned short h[8] = {
                    (unsigned short)(u.x & 0xFFFF), (unsigned short)(u.x >> 16),
                    (unsigned short)(u.y & 0xFFFF), (unsigned short)(u.y >> 16),
                    (unsigned short)(u.z & 0xFFFF), (unsigned short)(u.z >> 16),
                    (unsigned short)(u.w & 0xFFFF), (unsigned short)(u.w >> 16)};
                #pragma unroll
                for (int k = 0; k < 8; k++)
                    if ((h[k] & 0x8000) == 0 && h[k] != 0) bits |= (1u << k);
            } else {
                const float4* p = (const float4*)((const float*)adj + (size_t)i * N_NODES);
                float4 f = p[ch * 64 + lane];
                j0 = (ch * 64 + lane) * 4; nelem = 4;
                if (f.x > 0.f) bits |= 1u;
                if (f.y > 0.f) bits |= 2u;
                if (f.z > 0.f) bits |= 4u;
                if (f.w > 0.f) bits |= 8u;
            }
            int cnt = __popc(bits);
            int sc = cnt;
            #pragma unroll
            for (int off = 1; off < 64; off <<= 1) {
                int v = __shfl_up(sc, off);
                if (lane >= off) sc += v;
            }
            int tot = __shfl(sc, 63);
            int pos = base_out + running + (sc - cnt);
            for (int k = 0; k < nelem; k++) {
                if ((bits >> k) & 1u) {
                    if (pos < base_out + STRIDE) col_buf[pos] = j0 + k;
                    pos++;
                }
            }
            running += tot;
        }
        if (lane == 0) deg[i] = (running < STRIDE) ? running : STRIDE;
    }
}

// ---------------------------------------------------------------------------
// Routing iteration: 2048 blocks x 256 thr. TWO waves per node
// (node = blockIdx*2 + (w>>1); half = w&1), edge list split at an 8-aligned
// midpoint so int4 LDS reads stay aligned. Partials combined once in LDS.
// __launch_bounds__(256,8) caps VGPR at 64 -> 32 waves/CU (coop variant of
// the same core compiled to 40 VGPR, so no spill expected). Gives 2x the
// outstanding 1KB gathers per CU vs R2 (128 vs 64) + half the per-wave chain.
// Per-edge math unchanged: dot reduce on VALU DPP (3 adds), channel softmax
// via row_ror:8 DPP + shfl_xor 16/32, exp2 on log2e-pre-scaled zi.
// Lane: g = lane>>3 (channel), s = lane&7 (dim octet).
// ---------------------------------------------------------------------------
__device__ __forceinline__ void edge_step(const float zil2[8], float acc[8], uint4 u) {
    float vj[8];
    unpack2(u.x, vj[0], vj[1]);
    unpack2(u.y, vj[2], vj[3]);
    unpack2(u.z, vj[4], vj[5]);
    unpack2(u.w, vj[6], vj[7]);
    float p = 0.f;
    #pragma unroll
    for (int k = 0; k < 8; k++) p = fmaf(zil2[k], vj[k], p);
    // reduce over s (8 lanes) entirely on the VALU pipe
    p = dpp_add<0xB1>(p);      // xor1
    p = dpp_add<0x4E>(p);      // xor2
    p = dpp_add<0x141>(p);     // quad swap within 8
    float ex = __builtin_amdgcn_exp2f(p);   // exp(dot): zil2 pre-scaled by log2e
    // channel sum: stride 8 on DPP; strides 16/32 via DS shuffle
    float s = dpp_add<0x128>(ex);       // row_ror:8
    s += __shfl_xor(s, 16);
    s += __shfl_xor(s, 32);
    float wgt = ex * __builtin_amdgcn_rcpf(s);
    #pragma unroll
    for (int k = 0; k < 8; k++) acc[k] = fmaf(wgt, vj[k], acc[k]);
}

// l2-normalize acc over the 8 s-lanes of this channel group, write zi.
__device__ __forceinline__ void finish_norm(float acc[8], float zi[8]) {
    float ss = 0.f;
    #pragma unroll
    for (int k = 0; k < 8; k++) ss = fmaf(acc[k], acc[k], ss);
    ss = dpp_add<0xB1>(ss);
    ss = dpp_add<0x4E>(ss);
    ss = dpp_add<0x141>(ss);
    float sc = __builtin_amdgcn_rsqf(fmaxf(ss, 1e-12f));
    #pragma unroll
    for (int k = 0; k < 8; k++) zi[k] = acc[k] * sc;
}

__global__ __launch_bounds__(256, 8) void route_iter(
        const unsigned* __restrict__ bin_u, unsigned* __restrict__ bot,
        const int* __restrict__ deg, const int* __restrict__ col_buf) {
    const float LOG2E = 1.4426950408889634f;
    int t = threadIdx.x;
    int w = t >> 6, lane = t & 63;
    int local = w >> 1;                 // node within block: 0 or 1
    int half  = w & 1;                  // edge-list half
    int node = blockIdx.x * 2 + local;
    int g = lane >> 3, s = lane & 7;

    __shared__ __align__(16) int   s_cols[2 * STRIDE];   // 1 KB
    __shared__ __align__(16) float s_acc[2][CD];         // 4 KB
    s_cols[t] = col_buf[(size_t)blockIdx.x * (2 * STRIDE) + t] & (N_NODES - 1);
    int dg = deg[node];
    __syncthreads();
    const int* mycols = s_cols + local * STRIDE;

    int frag = g * 32 + s * 4;              // dword index within 256-dword row
    unsigned fragb = (unsigned)frag << 2;   // byte offset within 1 KB row

    uint4 uown = *(const uint4*)(bin_u + (size_t)node * 256 + frag);
    float zi[8], zil2[8], acc[8];
    unpack2(uown.x, zi[0], zi[1]); unpack2(uown.y, zi[2], zi[3]);
    unpack2(uown.z, zi[4], zi[5]); unpack2(uown.w, zi[6], zi[7]);
    #pragma unroll
    for (int k = 0; k < 8; k++) {
        zil2[k] = zi[k] * LOG2E;
        acc[k] = half ? 0.f : zi[k];        // residual added once (half 0)
    }

    // 8-aligned split point: both halves start int4-aligned in s_cols.
    int h0 = ((dg >> 1) + 7) & ~7;
    if (h0 > dg) h0 = dg;
    int e   = half ? h0 : 0;
    int end = half ? dg : h0;

    const char* bin = (const char*)bin_u;
    for (; e + 3 < end; e += 4) {
        int4 js = *(const int4*)&mycols[e];       // one ds_read_b128
        uint4 u0 = *(const uint4*)(bin + (((unsigned)js.x << 10) + fragb));
        uint4 u1 = *(const uint4*)(bin + (((unsigned)js.y << 10) + fragb));
        uint4 u2 = *(const uint4*)(bin + (((unsigned)js.z << 10) + fragb));
        uint4 u3 = *(const uint4*)(bin + (((unsigned)js.w << 10) + fragb));
        edge_step(zil2, acc, u0);
        edge_step(zil2, acc, u1);
        edge_step(zil2, acc, u2);
        edge_step(zil2, acc, u3);
    }
    for (; e < end; e++) {
        uint4 u0 = *(const uint4*)(bin + (((unsigned)mycols[e] << 10) + fragb));
        edge_step(zil2, acc, u0);
    }

    int flat = g * D_DIM + s * 8;
    if (half) {
        *(float4*)&s_acc[local][flat]     = make_float4(acc[0], acc[1], acc[2], acc[3]);
        *(float4*)&s_acc[local][flat + 4] = make_float4(acc[4], acc[5], acc[6], acc[7]);
    }
    __syncthreads();
    if (!half) {
        float4 p0 = *(const float4*)&s_acc[local][flat];
        float4 p1 = *(const float4*)&s_acc[local][flat + 4];
        acc[0] += p0.x; acc[1] += p0.y; acc[2] += p0.z; acc[3] += p0.w;
        acc[4] += p1.x; acc[5] += p1.y; acc[6] += p1.z; acc[7] += p1.w;

        finish_norm(acc, zi);

        uint4 ob;
        ob.x = pack2bf(zi[0], zi[1]); ob.y = pack2bf(zi[2], zi[3]);
        ob.z = pack2bf(zi[4], zi[5]); ob.w = pack2bf(zi[6], zi[7]);
        *(uint4*)(bot + (size_t)node * 256 + frag) = ob;
    }
}

// ---------------------------------------------------------------------------
// Final GEMM via MFMA bf16: out[4096x128] = zbf[4096x512] @ Wo + bias.
// ---------------------------------------------------------------------------
__global__ __launch_bounds__(256) void out_gemm_mfma(
        const unsigned* __restrict__ zbf, const unsigned* __restrict__ wot_u,
        const void* __restrict__ bias, void* __restrict__ out,
        const void* __restrict__ feat) {
    bool isbf = wave_detect((const unsigned*)feat);
    int w = threadIdx.x >> 6, lane = threadIdx.x & 63;
    int r0 = blockIdx.x * 32 + (w & 1) * 16;
    int n0 = (w >> 1) * 64;
    int m = lane & 15, quad = lane >> 4;

    floatx4 acc0 = {0.f, 0.f, 0.f, 0.f}, acc1 = acc0, acc2 = acc0, acc3 = acc0;
    const unsigned* ap  = zbf   + (size_t)(r0 + m) * 256 + quad * 4;
    const unsigned* bp0 = wot_u + (size_t)(n0 + m) * 256 + quad * 4;
    const unsigned* bp1 = bp0 + 16 * 256;
    const unsigned* bp2 = bp0 + 32 * 256;
    const unsigned* bp3 = bp0 + 48 * 256;

    #pragma unroll
    for (int k0 = 0; k0 < 256; k0 += 16) {
        short8 a  = as_s8(*(const uint4*)(ap  + k0));
        short8 b0 = as_s8(*(const uint4*)(bp0 + k0));
        short8 b1 = as_s8(*(const uint4*)(bp1 + k0));
        short8 b2 = as_s8(*(const uint4*)(bp2 + k0));
        short8 b3 = as_s8(*(const uint4*)(bp3 + k0));
        acc0 = __builtin_amdgcn_mfma_f32_16x16x32_bf16(a, b0, acc0, 0, 0, 0);
        acc1 = __builtin_amdgcn_mfma_f32_16x16x32_bf16(a, b1, acc1, 0, 0, 0);
        acc2 = __builtin_amdgcn_mfma_f32_16x16x32_bf16(a, b2, acc2, 0, 0, 0);
        acc3 = __builtin_amdgcn_mfma_f32_16x16x32_bf16(a, b3, acc3, 0, 0, 0);
    }

    float accs[4][4] = {
        {acc0[0], acc0[1], acc0[2], acc0[3]},
        {acc1[0], acc1[1], acc1[2], acc1[3]},
        {acc2[0], acc2[1], acc2[2], acc2[3]},
        {acc3[0], acc3[1], acc3[2], acc3[3]}};
    #pragma unroll
    for (int c = 0; c < 4; c++) {
        int col = n0 + c * 16 + m;
        float bb = isbf ? bf2f(((const bf16*)bias)[col]) : ((const float*)bias)[col];
        #pragma unroll
        for (int r = 0; r < 4; r++) {
            int row = r0 + quad * 4 + r;
            float v = accs[c][r] + bb;
            size_t oi = (size_t)row * OUT_DIM + col;
            if (isbf) ((bf16*)out)[oi] = __float2bfloat16(v);
            else      ((float*)out)[oi] = v;
        }
    }
}

// ---------------------------------------------------------------------------
extern "C" void kernel_launch(void* const* d_in, const int* in_sizes, int n_in,
                              void* d_out, int out_size, void* d_ws, size_t ws_size,
                              hipStream_t stream) {
    const void* feat = d_in[0];
    const void* adj  = d_in[1];
    const void* W    = d_in[2];
    const void* b    = d_in[3];
    const void* Wo   = d_in[4];
    const void* bias = d_in[5];

    char* ws = (char*)d_ws;
    unsigned*       zbf_a   = (unsigned*)ws;                                // 4 MB
    unsigned*       zbf_b   = (unsigned*)(ws + (4u << 20));                 // 4 MB
    unsigned short* Wt      = (unsigned short*)(ws + (8u << 20));           // 256 KB
    unsigned short* Wo_t    = (unsigned short*)(ws + (8u << 20) + (256u << 10)); // 128 KB
    int*            deg     = (int*)(ws + (8u << 20) + (512u << 10));       // 16 KB
    int*            col_buf = (int*)(ws + (9u << 20));                      // 2 MB

    stage_a<<<72, 256, 0, stream>>>(feat, W, Wo, Wt, Wo_t);
    stage_b<<<1280, 256, 0, stream>>>(feat, adj, b, Wt, zbf_a, deg, col_buf);

    unsigned* bin = zbf_a;
    unsigned* bot = zbf_b;
    for (int it = 0; it < ITERS; it++) {
        route_iter<<<N_NODES / 2, 256, 0, stream>>>(bin, bot, deg, col_buf);
        unsigned* tb = bin; bin = bot; bot = tb;
    }

    // ITERS=4 even -> final state back in zbf_a
    out_gemm_mfma<<<N_NODES / 32, 256, 0, stream>>>(zbf_a, (const unsigned*)Wo_t,
                                                    bias, d_out, feat);
}

// Round 4
// 206.614 us; speedup vs baseline: 1.0337x; 1.0086x over previous
//
#include <hip/hip_runtime.h>
#include <hip/hip_bf16.h>

#define N_NODES 4096
#define C_CH    8
#define IN_DIM  256
#define D_DIM   64
#define CD      512
#define OUT_DIM 128
#define ITERS   4
#define STRIDE  128     // max degree slack (mean 41, sd 6.4; 128 is >13 sigma)

typedef __hip_bfloat16 bf16;
typedef short short8 __attribute__((ext_vector_type(8)));
typedef float floatx4 __attribute__((ext_vector_type(4)));
typedef unsigned uintx4 __attribute__((ext_vector_type(4)));
typedef unsigned short ushortx4 __attribute__((ext_vector_type(4)));

__device__ __forceinline__ float bf2f(bf16 x) { return __bfloat162float(x); }

__device__ __forceinline__ unsigned f2b_rne(float x) {
    unsigned u = __float_as_uint(x);
    return (u + 0x7FFFu + ((u >> 16) & 1u)) >> 16;
}
__device__ __forceinline__ unsigned pack2bf(float a, float b) {
    return f2b_rne(a) | (f2b_rne(b) << 16);
}
__device__ __forceinline__ void unpack2(unsigned v, float& a, float& b) {
    a = __uint_as_float(v << 16);
    b = __uint_as_float(v & 0xFFFF0000u);
}
__device__ __forceinline__ short8 as_s8(uint4 u) {
    union { uint4 a; short8 b; } x; x.a = u; return x.b;
}

// VALU-pipe butterfly step: x + dpp_move(x). No DS unit involvement.
// CTRL: 0xB1 = quad_perm(1,0,3,2) -> xor1 ; 0x4E = quad_perm(2,3,0,1) -> xor2
//       0x141 = row_half_mirror -> quad swap within 8 ; 0x128 = row_ror:8
template<int CTRL>
__device__ __forceinline__ float dpp_add(float x) {
    int yi = __builtin_amdgcn_update_dpp(0, __float_as_int(x), CTRL, 0xF, 0xF, true);
    return x + __int_as_float(yi);
}

// Per-wave dtype detect from first 64 dwords of features.
__device__ __forceinline__ bool wave_detect(const unsigned* __restrict__ feat_u) {
    int lane = threadIdx.x & 63;
    unsigned u = feat_u[lane];
    int e = (u >> 7) & 0xFF;
    int vote = (e >= 0x68 && e <= 0x86) ? 1 : 0;
    #pragma unroll
    for (int off = 32; off; off >>= 1) vote += __shfl_xor(vote, off);
    return vote >= 32;
}

// ---------------------------------------------------------------------------
// Stage A: blocks [0,8) -> Wt[col][k] bf16 (LDS-tiled transpose of W);
//          blocks [8,72) -> Wo_t[n][k] bf16.
// ---------------------------------------------------------------------------
__global__ __launch_bounds__(256) void stage_a(
        const void* __restrict__ feat, const void* __restrict__ W,
        const void* __restrict__ Wo,
        unsigned short* __restrict__ Wt, unsigned short* __restrict__ Wo_t) {
    bool isbf = wave_detect((const unsigned*)feat);
    int bx = blockIdx.x, t = threadIdx.x;
    if (bx < 8) {
        __shared__ __align__(16) unsigned short lt[IN_DIM * D_DIM];   // 32 KB [k][d]
        int c = bx;
        if (isbf) {
            const uint4* p = (const uint4*)((const unsigned short*)W + (size_t)c * IN_DIM * D_DIM);
            #pragma unroll
            for (int i = 0; i < 8; i++) {
                int idx = t + i * 256;
                *(uint4*)&lt[idx * 8] = p[idx];
            }
        } else {
            const float4* p = (const float4*)((const float*)W + (size_t)c * IN_DIM * D_DIM);
            #pragma unroll
            for (int i = 0; i < 16; i++) {
                int idx = t + i * 256;
                float4 f = p[idx];
                uint2 v = make_uint2(pack2bf(f.x, f.y), pack2bf(f.z, f.w));
                *(uint2*)&lt[idx * 4] = v;
            }
        }
        __syncthreads();
        uint4* wt4 = (uint4*)Wt;
        #pragma unroll
        for (int i = 0; i < 8; i++) {
            int j = t + i * 256;
            int d = j >> 5, seg = j & 31;
            int k0 = seg * 8;
            unsigned short v[8];
            #pragma unroll
            for (int k = 0; k < 8; k++) v[k] = lt[(k0 + k) * D_DIM + d];
            uint4 o;
            o.x = v[0] | ((unsigned)v[1] << 16);
            o.y = v[2] | ((unsigned)v[3] << 16);
            o.z = v[4] | ((unsigned)v[5] << 16);
            o.w = v[6] | ((unsigned)v[7] << 16);
            wt4[(c * 64 + d) * 32 + seg] = o;
        }
    } else {
        int base = (bx - 8) * 1024 + t * 4;
        #pragma unroll
        for (int q = 0; q < 4; q++) {
            int idx = base + q;
            int k = idx >> 7, n = idx & 127;
            unsigned short v;
            if (isbf) v = ((const unsigned short*)Wo)[idx];
            else      v = (unsigned short)f2b_rne(((const float*)Wo)[idx]);
            Wo_t[n * CD + k] = v;
        }
    }
}

// ---------------------------------------------------------------------------
// Stage B: blocks [0,256) -> MFMA projection (16 rows x 512 cols per block,
// wave w covers cols w*128.. = channels 2w,2w+1); blocks [256,1280) -> build.
// C/D layout: col=lane&15, row=quad*4+reg (HW-verified).
// col_buf is u16 (j < 4096): halves the per-iteration edge-list stream.
// ---------------------------------------------------------------------------
__global__ __launch_bounds__(256) void stage_b(
        const void* __restrict__ feat, const void* __restrict__ adj,
        const void* __restrict__ b, const unsigned short* __restrict__ Wt,
        unsigned* __restrict__ zbf, int* __restrict__ deg,
        unsigned short* __restrict__ col_buf) {
    bool isbf = wave_detect((const unsigned*)feat);
    int bx = blockIdx.x, t = threadIdx.x;
    int w = t >> 6, lane = t & 63;
    __shared__ __align__(16) unsigned short zt[16 * CD];   // 16 KB

    if (bx < 256) {
        int r0 = bx * 16;
        int n0 = w * 128;
        int m = lane & 15, quad = lane >> 4;
        int row = r0 + m;
        floatx4 acc[8];
        #pragma unroll
        for (int j = 0; j < 8; j++) acc[j] = (floatx4){0.f, 0.f, 0.f, 0.f};
        const uint4* wt4 = (const uint4*)Wt;

        if (isbf) {
            const uint4* a4 = (const uint4*)feat + (size_t)row * 32 + quad;
            #pragma unroll
            for (int k0 = 0; k0 < 8; k0++) {
                short8 a = as_s8(a4[k0 * 4]);
                #pragma unroll
                for (int j = 0; j < 8; j++) {
                    int col = n0 + j * 16 + m;
                    short8 bb = as_s8(wt4[col * 32 + k0 * 4 + quad]);
                    acc[j] = __builtin_amdgcn_mfma_f32_16x16x32_bf16(a, bb, acc[j], 0, 0, 0);
                }
            }
        } else {
            const float4* a4 = (const float4*)feat + (size_t)row * 64 + quad * 2;
            #pragma unroll
            for (int k0 = 0; k0 < 8; k0++) {
                float4 f0 = a4[k0 * 8], f1 = a4[k0 * 8 + 1];
                uint4 au;
                au.x = pack2bf(f0.x, f0.y); au.y = pack2bf(f0.z, f0.w);
                au.z = pack2bf(f1.x, f1.y); au.w = pack2bf(f1.z, f1.w);
                short8 a = as_s8(au);
                #pragma unroll
                for (int j = 0; j < 8; j++) {
                    int col = n0 + j * 16 + m;
                    short8 bb = as_s8(wt4[col * 32 + k0 * 4 + quad]);
                    acc[j] = __builtin_amdgcn_mfma_f32_16x16x32_bf16(a, bb, acc[j], 0, 0, 0);
                }
            }
        }

        float pre[8][4];
        #pragma unroll
        for (int j = 0; j < 8; j++) {
            int col = n0 + j * 16 + m;
            float bb = isbf ? bf2f(((const bf16*)b)[col]) : ((const float*)b)[col];
            #pragma unroll
            for (int r = 0; r < 4; r++) pre[j][r] = acc[j][r] + bb;
        }
        #pragma unroll
        for (int ch = 0; ch < 2; ch++) {
            float ss[4];
            #pragma unroll
            for (int r = 0; r < 4; r++) {
                float s = 0.f;
                #pragma unroll
                for (int jj = 0; jj < 4; jj++) {
                    float v = pre[ch * 4 + jj][r];
                    s = fmaf(v, v, s);
                }
                ss[r] = s;
            }
            #pragma unroll
            for (int off = 1; off < 16; off <<= 1) {
                #pragma unroll
                for (int r = 0; r < 4; r++) ss[r] += __shfl_xor(ss[r], off);
            }
            #pragma unroll
            for (int r = 0; r < 4; r++) {
                float sc = __builtin_amdgcn_rsqf(fmaxf(ss[r], 1e-12f));
                int lrow = quad * 4 + r;
                #pragma unroll
                for (int jj = 0; jj < 4; jj++) {
                    int j = ch * 4 + jj;
                    int col = n0 + j * 16 + m;
                    zt[lrow * CD + col] = (unsigned short)f2b_rne(pre[j][r] * sc);
                }
            }
        }
        __syncthreads();
        const uint4* zt4 = (const uint4*)zt;
        uint4* z4 = (uint4*)zbf;
        #pragma unroll
        for (int i = 0; i < 4; i++) {
            int j = t + i * 256;
            int lrow = j >> 6, seg = j & 63;
            z4[(size_t)(r0 + lrow) * 64 + seg] = zt4[j];
        }
    } else {
        // ----- build: one wave per adjacency row, shfl scan
        int i = (bx - 256) * 4 + w;
        int base_out = i * STRIDE;
        int running = 0;
        int nch = isbf ? 8 : 16;
        for (int ch = 0; ch < nch; ch++) {
            unsigned bits = 0;
            int j0, nelem;
            if (isbf) {
                const uint4* p = (const uint4*)((const unsigned short*)adj + (size_t)i * N_NODES);
                uint4 u = p[ch * 64 + lane];
                j0 = (ch * 64 + lane) * 8; nelem = 8;
                unsigned short h[8] = {
                    (unsigned short)(u.x & 0xFFFF), (unsigned short)(u.x >> 16),
                    (unsigned short)(u.y & 0xFFFF), (unsigned short)(u.y >> 16),
                    (unsigned short)(u.z & 0xFFFF), (unsigned short)(u.z >> 16),
                    (unsigned short)(u.w & 0xFFFF), (unsigned short)(u.w >> 16)};
                #pragma unroll
                for (int k = 0; k < 8; k++)
                    if ((h[k] & 0x8000) == 0 && h[k] != 0) bits |= (1u << k);
            } else {
                const float4* p = (const float4*)((const float*)adj + (size_t)i * N_NODES);
                float4 f = p[ch * 64 + lane];
                j0 = (ch * 64 + lane) * 4; nelem = 4;
                if (f.x > 0.f) bits |= 1u;
                if (f.y > 0.f) bits |= 2u;
                if (f.z > 0.f) bits |= 4u;
                if (f.w > 0.f) bits |= 8u;
            }
            int cnt = __popc(bits);
            int sc = cnt;
            #pragma unroll
            for (int off = 1; off < 64; off <<= 1) {
                int v = __shfl_up(sc, off);
                if (lane >= off) sc += v;
            }
            int tot = __shfl(sc, 63);
            int pos = base_out + running + (sc - cnt);
            for (int k = 0; k < nelem; k++) {
                if ((bits >> k) & 1u) {
                    if (pos < base_out + STRIDE) col_buf[pos] = (unsigned short)(j0 + k);
                    pos++;
                }
            }
            running += tot;
        }
        if (lane == 0) deg[i] = (running < STRIDE) ? running : STRIDE;
    }
}

// ---------------------------------------------------------------------------
// Routing iteration: 2048 blocks x 256 thr. TWO waves per node
// (node = blockIdx*2 + (w>>1); half = w&1), edge list split at an 8-aligned
// midpoint; partials combined once in LDS. __launch_bounds__(256,8) -> 32
// waves/CU. KEY CHANGE vs R3: z_out stores are NON-TEMPORAL (nt) so the
// 4 MB/iter write stream stops thrashing the 4 MB/XCD L2 that must keep
// z_in resident for the 168 MB/iter of gathers. col_buf is u16.
// Per-edge math unchanged: dot reduce on VALU DPP (3 adds), channel softmax
// via row_ror:8 DPP + shfl_xor 16/32, exp2 on log2e-pre-scaled zi.
// Lane: g = lane>>3 (channel), s = lane&7 (dim octet).
// ---------------------------------------------------------------------------
__device__ __forceinline__ void edge_step(const float zil2[8], float acc[8], uint4 u) {
    float vj[8];
    unpack2(u.x, vj[0], vj[1]);
    unpack2(u.y, vj[2], vj[3]);
    unpack2(u.z, vj[4], vj[5]);
    unpack2(u.w, vj[6], vj[7]);
    float p = 0.f;
    #pragma unroll
    for (int k = 0; k < 8; k++) p = fmaf(zil2[k], vj[k], p);
    // reduce over s (8 lanes) entirely on the VALU pipe
    p = dpp_add<0xB1>(p);      // xor1
    p = dpp_add<0x4E>(p);      // xor2
    p = dpp_add<0x141>(p);     // quad swap within 8
    float ex = __builtin_amdgcn_exp2f(p);   // exp(dot): zil2 pre-scaled by log2e
    // channel sum: stride 8 on DPP; strides 16/32 via DS shuffle
    float s = dpp_add<0x128>(ex);       // row_ror:8
    s += __shfl_xor(s, 16);
    s += __shfl_xor(s, 32);
    float wgt = ex * __builtin_amdgcn_rcpf(s);
    #pragma unroll
    for (int k = 0; k < 8; k++) acc[k] = fmaf(wgt, vj[k], acc[k]);
}

// l2-normalize acc over the 8 s-lanes of this channel group, write zi.
__device__ __forceinline__ void finish_norm(float acc[8], float zi[8]) {
    float ss = 0.f;
    #pragma unroll
    for (int k = 0; k < 8; k++) ss = fmaf(acc[k], acc[k], ss);
    ss = dpp_add<0xB1>(ss);
    ss = dpp_add<0x4E>(ss);
    ss = dpp_add<0x141>(ss);
    float sc = __builtin_amdgcn_rsqf(fmaxf(ss, 1e-12f));
    #pragma unroll
    for (int k = 0; k < 8; k++) zi[k] = acc[k] * sc;
}

__global__ __launch_bounds__(256, 8) void route_iter(
        const unsigned* __restrict__ bin_u, unsigned* __restrict__ bot,
        const int* __restrict__ deg, const unsigned short* __restrict__ col_buf) {
    const float LOG2E = 1.4426950408889634f;
    int t = threadIdx.x;
    int w = t >> 6, lane = t & 63;
    int local = w >> 1;                 // node within block: 0 or 1
    int half  = w & 1;                  // edge-list half
    int node = blockIdx.x * 2 + local;
    int g = lane >> 3, s = lane & 7;

    __shared__ __align__(16) unsigned short s_cols[2 * STRIDE];  // 512 B
    __shared__ __align__(16) float s_acc[2][CD];                 // 4 KB
    if (t < 128) {
        ((unsigned*)s_cols)[t] =
            ((const unsigned*)(col_buf + (size_t)blockIdx.x * (2 * STRIDE)))[t];
    }
    int dg = deg[node];
    __syncthreads();
    const unsigned short* mycols = s_cols + local * STRIDE;

    int frag = g * 32 + s * 4;              // dword index within 256-dword row
    unsigned fragb = (unsigned)frag << 2;   // byte offset within 1 KB row

    uint4 uown = *(const uint4*)(bin_u + (size_t)node * 256 + frag);
    float zi[8], zil2[8], acc[8];
    unpack2(uown.x, zi[0], zi[1]); unpack2(uown.y, zi[2], zi[3]);
    unpack2(uown.z, zi[4], zi[5]); unpack2(uown.w, zi[6], zi[7]);
    #pragma unroll
    for (int k = 0; k < 8; k++) {
        zil2[k] = zi[k] * LOG2E;
        acc[k] = half ? 0.f : zi[k];        // residual added once (half 0)
    }

    // 8-aligned split point: both halves start 8B-aligned in s_cols.
    int h0 = ((dg >> 1) + 7) & ~7;
    if (h0 > dg) h0 = dg;
    int e   = half ? h0 : 0;
    int end = half ? dg : h0;

    const char* bin = (const char*)bin_u;
    for (; e + 3 < end; e += 4) {
        ushortx4 js = *(const ushortx4*)&mycols[e];   // one ds_read_b64
        uint4 u0 = *(const uint4*)(bin + (((unsigned)js.x << 10) + fragb));
        uint4 u1 = *(const uint4*)(bin + (((unsigned)js.y << 10) + fragb));
        uint4 u2 = *(const uint4*)(bin + (((unsigned)js.z << 10) + fragb));
        uint4 u3 = *(const uint4*)(bin + (((unsigned)js.w << 10) + fragb));
        edge_step(zil2, acc, u0);
        edge_step(zil2, acc, u1);
        edge_step(zil2, acc, u2);
        edge_step(zil2, acc, u3);
    }
    for (; e < end; e++) {
        unsigned j0 = mycols[e];
        uint4 u0 = *(const uint4*)(bin + ((j0 << 10) + fragb));
        edge_step(zil2, acc, u0);
    }

    int flat = g * D_DIM + s * 8;
    if (half) {
        *(float4*)&s_acc[local][flat]     = make_float4(acc[0], acc[1], acc[2], acc[3]);
        *(float4*)&s_acc[local][flat + 4] = make_float4(acc[4], acc[5], acc[6], acc[7]);
    }
    __syncthreads();
    if (!half) {
        float4 p0 = *(const float4*)&s_acc[local][flat];
        float4 p1 = *(const float4*)&s_acc[local][flat + 4];
        acc[0] += p0.x; acc[1] += p0.y; acc[2] += p0.z; acc[3] += p0.w;
        acc[4] += p1.x; acc[5] += p1.y; acc[6] += p1.z; acc[7] += p1.w;

        finish_norm(acc, zi);

        // Non-temporal store: keep the z_out stream out of L2 so z_in stays
        // resident for the gather traffic (the L2-thrash fix).
        uintx4 ob;
        ob.x = pack2bf(zi[0], zi[1]); ob.y = pack2bf(zi[2], zi[3]);
        ob.z = pack2bf(zi[4], zi[5]); ob.w = pack2bf(zi[6], zi[7]);
        __builtin_nontemporal_store(
            ob, (uintx4*)(bot + (size_t)node * 256 + frag));
    }
}

// ---------------------------------------------------------------------------
// Final GEMM via MFMA bf16: out[4096x128] = zbf[4096x512] @ Wo + bias.
// ---------------------------------------------------------------------------
__global__ __launch_bounds__(256) void out_gemm_mfma(
        const unsigned* __restrict__ zbf, const unsigned* __restrict__ wot_u,
        const void* __restrict__ bias, void* __restrict__ out,
        const void* __restrict__ feat) {
    bool isbf = wave_detect((const unsigned*)feat);
    int w = threadIdx.x >> 6, lane = threadIdx.x & 63;
    int r0 = blockIdx.x * 32 + (w & 1) * 16;
    int n0 = (w >> 1) * 64;
    int m = lane & 15, quad = lane >> 4;

    floatx4 acc0 = {0.f, 0.f, 0.f, 0.f}, acc1 = acc0, acc2 = acc0, acc3 = acc0;
    const unsigned* ap  = zbf   + (size_t)(r0 + m) * 256 + quad * 4;
    const unsigned* bp0 = wot_u + (size_t)(n0 + m) * 256 + quad * 4;
    const unsigned* bp1 = bp0 + 16 * 256;
    const unsigned* bp2 = bp0 + 32 * 256;
    const unsigned* bp3 = bp0 + 48 * 256;

    #pragma unroll
    for (int k0 = 0; k0 < 256; k0 += 16) {
        short8 a  = as_s8(*(const uint4*)(ap  + k0));
        short8 b0 = as_s8(*(const uint4*)(bp0 + k0));
        short8 b1 = as_s8(*(const uint4*)(bp1 + k0));
        short8 b2 = as_s8(*(const uint4*)(bp2 + k0));
        short8 b3 = as_s8(*(const uint4*)(bp3 + k0));
        acc0 = __builtin_amdgcn_mfma_f32_16x16x32_bf16(a, b0, acc0, 0, 0, 0);
        acc1 = __builtin_amdgcn_mfma_f32_16x16x32_bf16(a, b1, acc1, 0, 0, 0);
        acc2 = __builtin_amdgcn_mfma_f32_16x16x32_bf16(a, b2, acc2, 0, 0, 0);
        acc3 = __builtin_amdgcn_mfma_f32_16x16x32_bf16(a, b3, acc3, 0, 0, 0);
    }

    float accs[4][4] = {
        {acc0[0], acc0[1], acc0[2], acc0[3]},
        {acc1[0], acc1[1], acc1[2], acc1[3]},
        {acc2[0], acc2[1], acc2[2], acc2[3]},
        {acc3[0], acc3[1], acc3[2], acc3[3]}};
    #pragma unroll
    for (int c = 0; c < 4; c++) {
        int col = n0 + c * 16 + m;
        float bb = isbf ? bf2f(((const bf16*)bias)[col]) : ((const float*)bias)[col];
        #pragma unroll
        for (int r = 0; r < 4; r++) {
            int row = r0 + quad * 4 + r;
            float v = accs[c][r] + bb;
            size_t oi = (size_t)row * OUT_DIM + col;
            if (isbf) ((bf16*)out)[oi] = __float2bfloat16(v);
            else      ((float*)out)[oi] = v;
        }
    }
}

// ---------------------------------------------------------------------------
extern "C" void kernel_launch(void* const* d_in, const int* in_sizes, int n_in,
                              void* d_out, int out_size, void* d_ws, size_t ws_size,
                              hipStream_t stream) {
    const void* feat = d_in[0];
    const void* adj  = d_in[1];
    const void* W    = d_in[2];
    const void* b    = d_in[3];
    const void* Wo   = d_in[4];
    const void* bias = d_in[5];

    char* ws = (char*)d_ws;
    unsigned*       zbf_a   = (unsigned*)ws;                                // 4 MB
    unsigned*       zbf_b   = (unsigned*)(ws + (4u << 20));                 // 4 MB
    unsigned short* Wt      = (unsigned short*)(ws + (8u << 20));           // 256 KB
    unsigned short* Wo_t    = (unsigned short*)(ws + (8u << 20) + (256u << 10)); // 128 KB
    int*            deg     = (int*)(ws + (8u << 20) + (512u << 10));       // 16 KB
    unsigned short* col_buf = (unsigned short*)(ws + (9u << 20));           // 1 MB

    stage_a<<<72, 256, 0, stream>>>(feat, W, Wo, Wt, Wo_t);
    stage_b<<<1280, 256, 0, stream>>>(feat, adj, b, Wt, zbf_a, deg, col_buf);

    unsigned* bin = zbf_a;
    unsigned* bot = zbf_b;
    for (int it = 0; it < ITERS; it++) {
        route_iter<<<N_NODES / 2, 256, 0, stream>>>(bin, bot, deg, col_buf);
        unsigned* tb = bin; bin = bot; bot = tb;
    }

    // ITERS=4 even -> final state back in zbf_a
    out_gemm_mfma<<<N_NODES / 32, 256, 0, stream>>>(zbf_a, (const unsigned*)Wo_t,
                                                    bias, d_out, feat);
}